// Round 1
// baseline (1027.297 us; speedup 1.0000x reference)
//
#include <hip/hip_runtime.h>
#include <math.h>

#define N_TOK 65536
#define D_DIM 256
#define C_NUM 1024

// d_out layout (floats): out (D*N) | indices (N) | loss (1) | distances (N*C)
#define OUT_OFF   0
#define IDX_OFF   (D_DIM * N_TOK)            // 16777216
#define LOSS_OFF  (IDX_OFF + N_TOK)          // 16842752
#define DIST_OFF  (LOSS_OFF + 1)             // 16842753

// ---------------------------------------------------------------------------
// k1: x2[n] -> out[IDX_OFF + n] (scratch, overwritten by k3 later)
//     e2[c] -> out[OUT_OFF + c] (scratch, overwritten by k4 later)
//     zero the loss accumulator.
// grid 512 x 256 threads: blocks 0..255 do x2, blocks 256..511 do e2.
// ---------------------------------------------------------------------------
__global__ __launch_bounds__(256) void k1_prep(const float* __restrict__ X,
                                               const float* __restrict__ E,
                                               float* __restrict__ out) {
  const int bid = blockIdx.x, tid = threadIdx.x;
  if (bid == 0 && tid == 0) out[LOSS_OFF] = 0.0f;
  if (bid < 256) {
    const int n = bid * 256 + tid;           // coalesced across lanes
    float s = 0.0f;
#pragma unroll 8
    for (int d = 0; d < D_DIM; ++d) {
      float v = X[(size_t)d * N_TOK + n];
      s = fmaf(v, v, s);
    }
    out[IDX_OFF + n] = s;
  } else {
    const int lane = tid & 63, w = tid >> 6;
    const int c = (bid - 256) * 4 + w;       // wave per codeword
    const float4 v = *(const float4*)(E + (size_t)c * D_DIM + lane * 4);
    float s = v.x * v.x + v.y * v.y + v.z * v.z + v.w * v.w;
#pragma unroll
    for (int off = 32; off; off >>= 1) s += __shfl_down(s, off, 64);
    if (lane == 0) out[OUT_OFF + c] = s;
  }
}

// ---------------------------------------------------------------------------
// k2: distances GEMM. Block tile 64 tokens x 64 codes, K chunked by 32 in LDS,
// 4x4 register micro-tile per thread (256 threads = 16x16).
// X is (d, n): rows are token-contiguous -> coalesced staging, no transpose.
// E is (c, d): float4 loads, transposed into LDS (stride 68 keeps b128-aligned
// rows and <=2-way bank aliasing on the micro-tile reads).
// ---------------------------------------------------------------------------
#define TM 64
#define TC 64
#define KB 32
#define ES_STRIDE 68

__global__ __launch_bounds__(256) void k2_dist(const float* __restrict__ X,
                                               const float* __restrict__ E,
                                               float* __restrict__ out) {
  __shared__ float xs[KB][TM];
  __shared__ float es[KB][ES_STRIDE];

  const int tid = threadIdx.x;
  const int c0 = blockIdx.x * TC;            // x fastest: 16 c-tiles share X tile in L2
  const int n0 = blockIdx.y * TM;
  const int tx = tid & 15;                   // -> 4 codes
  const int ty = tid >> 4;                   // -> 4 tokens

  float acc[4][4] = {};

  for (int kb = 0; kb < D_DIM; kb += KB) {
    // stage X: xs[r][t] = X[(kb+r)*N + n0 + t]; 64 consecutive floats per row
    {
      const int t = tid & 63;
      const int r0 = tid >> 6;
#pragma unroll
      for (int i = 0; i < 8; ++i) {
        const int r = r0 + i * 4;
        xs[r][t] = X[(size_t)(kb + r) * N_TOK + n0 + t];
      }
    }
    // stage E transposed: es[k][c] = E[(c0+c)*D + kb + k]
    {
      const int c = tid >> 2;
      const int k0 = (tid & 3) * 8;
#pragma unroll
      for (int j = 0; j < 2; ++j) {
        const float4 v =
            *(const float4*)(E + (size_t)(c0 + c) * D_DIM + kb + k0 + j * 4);
        es[k0 + j * 4 + 0][c] = v.x;
        es[k0 + j * 4 + 1][c] = v.y;
        es[k0 + j * 4 + 2][c] = v.z;
        es[k0 + j * 4 + 3][c] = v.w;
      }
    }
    __syncthreads();

#pragma unroll
    for (int k = 0; k < KB; ++k) {
      const float4 xv = *(const float4*)&xs[k][ty * 4];
      const float4 ev = *(const float4*)&es[k][tx * 4];
      acc[0][0] = fmaf(xv.x, ev.x, acc[0][0]);
      acc[0][1] = fmaf(xv.x, ev.y, acc[0][1]);
      acc[0][2] = fmaf(xv.x, ev.z, acc[0][2]);
      acc[0][3] = fmaf(xv.x, ev.w, acc[0][3]);
      acc[1][0] = fmaf(xv.y, ev.x, acc[1][0]);
      acc[1][1] = fmaf(xv.y, ev.y, acc[1][1]);
      acc[1][2] = fmaf(xv.y, ev.z, acc[1][2]);
      acc[1][3] = fmaf(xv.y, ev.w, acc[1][3]);
      acc[2][0] = fmaf(xv.z, ev.x, acc[2][0]);
      acc[2][1] = fmaf(xv.z, ev.y, acc[2][1]);
      acc[2][2] = fmaf(xv.z, ev.z, acc[2][2]);
      acc[2][3] = fmaf(xv.z, ev.w, acc[2][3]);
      acc[3][0] = fmaf(xv.w, ev.x, acc[3][0]);
      acc[3][1] = fmaf(xv.w, ev.y, acc[3][1]);
      acc[3][2] = fmaf(xv.w, ev.z, acc[3][2]);
      acc[3][3] = fmaf(xv.w, ev.w, acc[3][3]);
    }
    __syncthreads();
  }

  // epilogue: d2 = x2 + e2 - 2*xe; dist = -sqrt(max(d2,0))
  float x2v[4], e2v[4];
#pragma unroll
  for (int i = 0; i < 4; ++i) x2v[i] = out[IDX_OFF + n0 + ty * 4 + i];
#pragma unroll
  for (int j = 0; j < 4; ++j) e2v[j] = out[OUT_OFF + c0 + tx * 4 + j];

#pragma unroll
  for (int i = 0; i < 4; ++i) {
    const size_t row = (size_t)(n0 + ty * 4 + i) * C_NUM;
#pragma unroll
    for (int j = 0; j < 4; ++j) {
      float d2 = fmaf(-2.0f, acc[i][j], x2v[i] + e2v[j]);
      d2 = fmaxf(d2, 0.0f);
      out[DIST_OFF + row + c0 + tx * 4 + j] = -sqrtf(d2);
    }
  }
}

// ---------------------------------------------------------------------------
// k3: argmax per token over 1024 distances (wave per token, coalesced reads),
// first-index tie-break to match jnp.argmax. Loss partial = best^2 (== d2min).
// ---------------------------------------------------------------------------
__global__ __launch_bounds__(256) void k3_argmax(float* __restrict__ out) {
  __shared__ float lsum[4];
  const int tid = threadIdx.x, lane = tid & 63, w = tid >> 6;
  const int n = blockIdx.x * 4 + w;
  const float* row = out + DIST_OFF + (size_t)n * C_NUM;

  float best = -3.4e38f;
  int bi = 0;
#pragma unroll
  for (int j = 0; j < 16; ++j) {
    const float v = row[j * 64 + lane];      // coalesced 256B per wave-instr
    if (v > best) { best = v; bi = j * 64 + lane; }
  }
#pragma unroll
  for (int off = 32; off; off >>= 1) {
    const float ov = __shfl_xor(best, off, 64);
    const int oi = __shfl_xor(bi, off, 64);
    if (ov > best || (ov == best && oi < bi)) { best = ov; bi = oi; }
  }
  if (lane == 0) {
    out[IDX_OFF + n] = (float)bi;            // overwrites x2 scratch (k2 done)
    lsum[w] = best * best;                   // d2 at argmax
  }
  __syncthreads();
  if (tid == 0)
    atomicAdd(&out[LOSS_OFF], lsum[0] + lsum[1] + lsum[2] + lsum[3]);
}

// ---------------------------------------------------------------------------
// k4: out[d][n] = E[idx[n]][d] (straight-through output == quantized),
// coalesced writes per d-step; finalize loss.
// ---------------------------------------------------------------------------
__global__ __launch_bounds__(256) void k4_gather(const float* __restrict__ E,
                                                 float* __restrict__ out) {
  const int n = blockIdx.x * 256 + threadIdx.x;
  const int idx = (int)out[IDX_OFF + n];
  const float* e = E + (size_t)idx * D_DIM;
#pragma unroll 4
  for (int d = 0; d < D_DIM; ++d) {
    out[(size_t)d * N_TOK + n] = e[d];
  }
  if (blockIdx.x == 0 && threadIdx.x == 0) {
    out[LOSS_OFF] = out[LOSS_OFF] * (0.25f / ((float)N_TOK * (float)D_DIM));
  }
}

extern "C" void kernel_launch(void* const* d_in, const int* in_sizes, int n_in,
                              void* d_out, int out_size, void* d_ws, size_t ws_size,
                              hipStream_t stream) {
  const float* X = (const float*)d_in[0];   // (1, 256, 65536)
  const float* E = (const float*)d_in[1];   // (1, 1024, 256)
  float* out = (float*)d_out;

  hipLaunchKernelGGL(k1_prep, dim3(512), dim3(256), 0, stream, X, E, out);
  hipLaunchKernelGGL(k2_dist, dim3(C_NUM / TC, N_TOK / TM), dim3(256), 0, stream,
                     X, E, out);
  hipLaunchKernelGGL(k3_argmax, dim3(N_TOK / 4), dim3(256), 0, stream, out);
  hipLaunchKernelGGL(k4_gather, dim3(N_TOK / 256), dim3(256), 0, stream, E, out);
}

// Round 2
// 676.524 us; speedup vs baseline: 1.5185x; 1.5185x over previous
//
#include <hip/hip_runtime.h>
#include <math.h>

#define N_TOK 65536
#define D_DIM 256
#define C_NUM 1024

// d_out layout (floats): out (D*N) | indices (N) | loss (1) | distances (N*C)
#define OUT_OFF   0
#define IDX_OFF   (D_DIM * N_TOK)            // 16777216
#define LOSS_OFF  (IDX_OFF + N_TOK)          // 16842752
#define DIST_OFF  (LOSS_OFF + 1)             // 16842753

// scratch inside the out region (dead until k4 overwrites it):
//   EhG: 262144 u16 (= 131072 floats) at float-offset 0
//   ElG: 262144 u16 at float-offset 131072
//   e2 : 1024 floats at 262144
//   loss partials: 4096 floats at 263168
#define EH_OFF_F  0
#define EL_OFF_F  131072
#define E2_OFF_F  262144
#define PART_OFF_F 263168
#define NPART 4096

typedef __attribute__((ext_vector_type(8))) short bf16x8;
typedef __attribute__((ext_vector_type(4))) float f32x4;

static __device__ __forceinline__ unsigned short f2bf(float f) {
  unsigned int u = __float_as_uint(f);
  unsigned int r = (u + 0x7fffu + ((u >> 16) & 1u)) >> 16;
  return (unsigned short)r;
}
static __device__ __forceinline__ float bf2f(unsigned short h) {
  return __uint_as_float(((unsigned int)h) << 16);
}

// ---------------------------------------------------------------------------
// kA: blocks 0..255: x2[n] -> idx region (scratch). blocks 256..271: convert
// E -> (Eh,El) bf16 [c][k] + e2[c], wave per code (16 codes per wave).
// ---------------------------------------------------------------------------
__global__ __launch_bounds__(256) void kA_prep(const float* __restrict__ X,
                                               const float* __restrict__ E,
                                               float* __restrict__ out) {
  const int bid = blockIdx.x, tid = threadIdx.x;
  if (bid < 256) {
    const int n = bid * 256 + tid;
    float s = 0.0f;
#pragma unroll 8
    for (int d = 0; d < D_DIM; ++d) {
      float v = X[(size_t)d * N_TOK + n];
      s = fmaf(v, v, s);
    }
    out[IDX_OFF + n] = s;                    // x2 scratch
  } else {
    unsigned short* EhG = (unsigned short*)(out + EH_OFF_F);
    unsigned short* ElG = (unsigned short*)(out + EL_OFF_F);
    const int lane = tid & 63, w = tid >> 6;
#pragma unroll 1
    for (int cc = 0; cc < 16; ++cc) {
      const int c = (bid - 256) * 64 + w * 16 + cc;
      const float4 v = *(const float4*)(E + (size_t)c * D_DIM + lane * 4);
      unsigned short h0 = f2bf(v.x), h1 = f2bf(v.y), h2 = f2bf(v.z), h3 = f2bf(v.w);
      unsigned short l0 = f2bf(v.x - bf2f(h0)), l1 = f2bf(v.y - bf2f(h1));
      unsigned short l2 = f2bf(v.z - bf2f(h2)), l3 = f2bf(v.w - bf2f(h3));
      ushort4 hv = make_ushort4(h0, h1, h2, h3);
      ushort4 lv = make_ushort4(l0, l1, l2, l3);
      *(ushort4*)(EhG + (size_t)c * D_DIM + lane * 4) = hv;
      *(ushort4*)(ElG + (size_t)c * D_DIM + lane * 4) = lv;
      float s = v.x * v.x + v.y * v.y + v.z * v.z + v.w * v.w;
#pragma unroll
      for (int off = 32; off; off >>= 1) s += __shfl_down(s, off, 64);
      if (lane == 0) out[E2_OFF_F + c] = s;
    }
  }
}

// ---------------------------------------------------------------------------
// k2: distances via split-bf16 MFMA. Block = 64 tokens x 256 codes, 4 waves,
// wave w owns codes [w*64, w*64+64) as 4 n-tiles of 16. K chunk = 32.
// A (X) staged fp32->bf16 hi/lo into LDS ([n][k], stride 40 u16 = 80B,
// b128-aligned). B (E) frags loaded directly from preconverted global bf16
// [c][k] (1MB, L2-resident). 48 MFMAs : 8 LDS b128 reads per wave per chunk.
// ---------------------------------------------------------------------------
#define TM 64
#define TC 256
#define BK 32
#define XS 40   // u16 stride per token row (32 + 8 pad), 80B: 16B-aligned

__global__ __launch_bounds__(256) void k2_dist(const float* __restrict__ X,
                                               float* __restrict__ out) {
  __shared__ unsigned short xh[TM * XS];
  __shared__ unsigned short xl[TM * XS];

  const unsigned short* __restrict__ EhG = (const unsigned short*)(out + EH_OFF_F);
  const unsigned short* __restrict__ ElG = (const unsigned short*)(out + EL_OFF_F);

  const int tid = threadIdx.x;
  const int lane = tid & 63, wave = tid >> 6;
  const int c0 = blockIdx.x * TC;
  const int n0 = blockIdx.y * TM;
  const int wc = c0 + wave * 64;             // this wave's 64 codes
  const int m = lane & 15;                   // row/col within 16-tile
  const int q = lane >> 4;                   // k-quad

  f32x4 acc[4][4];                           // [m-tile][n-tile]
#pragma unroll
  for (int i = 0; i < 4; ++i)
#pragma unroll
    for (int t = 0; t < 4; ++t) acc[i][t] = (f32x4){0.f, 0.f, 0.f, 0.f};

  const int sn = lane;                       // staged token (0..63)
  const int kg = wave;                       // staged k-group (0..3) -> 8 k's

#pragma unroll 1
  for (int kb = 0; kb < D_DIM; kb += BK) {
    // ---- stage X chunk: fp32 -> bf16 hi/lo, transposed to [n][k] ----
    const float* xp = X + (size_t)(kb + kg * 8) * N_TOK + n0 + sn;
    float xv[8];
#pragma unroll
    for (int j = 0; j < 8; ++j) xv[j] = xp[(size_t)j * N_TOK];
    unsigned short hh[8], ll[8];
#pragma unroll
    for (int j = 0; j < 8; ++j) {
      hh[j] = f2bf(xv[j]);
      ll[j] = f2bf(xv[j] - bf2f(hh[j]));
    }
    *(bf16x8*)&xh[sn * XS + kg * 8] = *(bf16x8*)hh;
    *(bf16x8*)&xl[sn * XS + kg * 8] = *(bf16x8*)ll;
    __syncthreads();

    // ---- B fragments straight from global (L2-hot, 1MB total) ----
    bf16x8 bh[4], bl[4];
#pragma unroll
    for (int t = 0; t < 4; ++t) {
      const size_t eoff = (size_t)(wc + t * 16 + m) * D_DIM + kb + q * 8;
      bh[t] = *(const bf16x8*)(EhG + eoff);
      bl[t] = *(const bf16x8*)(ElG + eoff);
    }
    // ---- A fragments from LDS ----
    bf16x8 ah[4], al[4];
#pragma unroll
    for (int i = 0; i < 4; ++i) {
      const int ro = (i * 16 + m) * XS + q * 8;
      ah[i] = *(const bf16x8*)&xh[ro];
      al[i] = *(const bf16x8*)&xl[ro];
    }
    // ---- 48 MFMAs: hi*hi + hi*lo + lo*hi ----
#pragma unroll
    for (int i = 0; i < 4; ++i)
#pragma unroll
      for (int t = 0; t < 4; ++t) {
        acc[i][t] = __builtin_amdgcn_mfma_f32_16x16x32_bf16(ah[i], bh[t], acc[i][t], 0, 0, 0);
        acc[i][t] = __builtin_amdgcn_mfma_f32_16x16x32_bf16(ah[i], bl[t], acc[i][t], 0, 0, 0);
        acc[i][t] = __builtin_amdgcn_mfma_f32_16x16x32_bf16(al[i], bh[t], acc[i][t], 0, 0, 0);
      }
    __syncthreads();
  }

  // ---- epilogue: d2 = x2 + e2 - 2*xe; dist = -sqrt(max(d2,0)) ----
  float e2v[4];
#pragma unroll
  for (int t = 0; t < 4; ++t) e2v[t] = out[E2_OFF_F + wc + t * 16 + m];

#pragma unroll
  for (int i = 0; i < 4; ++i) {
#pragma unroll
    for (int r = 0; r < 4; ++r) {
      const int tok = n0 + i * 16 + q * 4 + r;
      const float x2v = out[IDX_OFF + tok];
      const size_t row = DIST_OFF + (size_t)tok * C_NUM;
#pragma unroll
      for (int t = 0; t < 4; ++t) {
        float d2 = fmaf(-2.0f, acc[i][t][r], x2v + e2v[t]);
        d2 = fmaxf(d2, 0.0f);
        out[row + wc + t * 16 + m] = -sqrtf(d2);
      }
    }
  }
}

// ---------------------------------------------------------------------------
// k3: wave per token (4 tokens per wave, 4 waves per block -> 16 tokens/blk).
// Approx argmax from stored distances; candidates within MARGIN of best get
// exact fp32 d2 (wave-cooperative), lexicographic (d2, idx) winner -> matches
// reference argmax incl. first-index tie-break. Per-block loss partial.
// ---------------------------------------------------------------------------
#define MARGIN 0.01f

__global__ __launch_bounds__(256) void k3_argmax(const float* __restrict__ X,
                                                 const float* __restrict__ E,
                                                 float* __restrict__ out) {
  __shared__ float lsum[4];
  const int tid = threadIdx.x, lane = tid & 63, w = tid >> 6;
  float wloss = 0.0f;

#pragma unroll 1
  for (int it = 0; it < 4; ++it) {
    const int n = blockIdx.x * 16 + w * 4 + it;
    const float* row = out + DIST_OFF + (size_t)n * C_NUM;

    float v[16];
    float best = -3.4e38f;
    int bi = 0x7fffffff;
#pragma unroll
    for (int j = 0; j < 16; ++j) {
      v[j] = row[j * 64 + lane];
      if (v[j] > best) { best = v[j]; bi = j * 64 + lane; }
    }
#pragma unroll
    for (int off = 32; off; off >>= 1) {
      const float ov = __shfl_xor(best, off, 64);
      const int oi = __shfl_xor(bi, off, 64);
      if (ov > best || (ov == best && oi < bi)) { best = ov; bi = oi; }
    }
    // candidate set within margin
    const float thr = best - MARGIN;
    unsigned long long masks[16];
    int total = 0;
#pragma unroll
    for (int j = 0; j < 16; ++j) {
      masks[j] = __ballot(v[j] > thr);
      total += __popcll(masks[j]);
    }
    float best_d2 = best * best;
    int best_idx = bi;
    if (total > 1) {
      best_d2 = 3.4e38f;
      best_idx = 0x7fffffff;
      for (int j = 0; j < 16; ++j) {
        unsigned long long mm = masks[j];
        while (mm) {
          const int l = __ffsll((long long)mm) - 1;
          mm &= mm - 1;
          const int c = j * 64 + l;
          // exact fp32 d2, wave-cooperative over d
          float sx = 0.f, se = 0.f, sxe = 0.f;
#pragma unroll
          for (int r = 0; r < 4; ++r) {
            const int d = r * 64 + lane;
            const float xv = X[(size_t)d * N_TOK + n];
            const float ev = E[(size_t)c * D_DIM + d];
            sx = fmaf(xv, xv, sx);
            se = fmaf(ev, ev, se);
            sxe = fmaf(xv, ev, sxe);
          }
          float d2 = fmaf(-2.f, sxe, sx + se);
#pragma unroll
          for (int off = 32; off; off >>= 1) d2 += __shfl_xor(d2, off, 64);
          d2 = fmaxf(d2, 0.f);
          if (d2 < best_d2 || (d2 == best_d2 && c < best_idx)) {
            best_d2 = d2; best_idx = c;
          }
        }
      }
    }
    if (lane == 0) out[IDX_OFF + n] = (float)best_idx;
    wloss += best_d2;
  }
  if (lane == 0) lsum[w] = wloss;
  __syncthreads();
  if (tid == 0)
    out[PART_OFF_F + blockIdx.x] = lsum[0] + lsum[1] + lsum[2] + lsum[3];
}

// ---------------------------------------------------------------------------
// k3b: reduce 4096 partials -> loss (single block; no contended atomics).
// ---------------------------------------------------------------------------
__global__ __launch_bounds__(256) void k3b_loss(float* __restrict__ out) {
  __shared__ float red[4];
  const int tid = threadIdx.x, lane = tid & 63, w = tid >> 6;
  float s = 0.0f;
#pragma unroll
  for (int i = 0; i < NPART / 256; ++i) s += out[PART_OFF_F + i * 256 + tid];
#pragma unroll
  for (int off = 32; off; off >>= 1) s += __shfl_down(s, off, 64);
  if (lane == 0) red[w] = s;
  __syncthreads();
  if (tid == 0)
    out[LOSS_OFF] = (red[0] + red[1] + red[2] + red[3]) *
                    (0.25f / ((float)N_TOK * (float)D_DIM));
}

// ---------------------------------------------------------------------------
// k4: out[d][n] = E[idx[n]][d]. Thread owns 4 consecutive n, float4 writes.
// grid (64, 8): y-splits d for occupancy. Overwrites the scratch region last.
// ---------------------------------------------------------------------------
__global__ __launch_bounds__(256) void k4_gather(const float* __restrict__ E,
                                                 float* __restrict__ out) {
  const int g = blockIdx.x * 256 + threadIdx.x;   // n-group
  const int n = g * 4;
  const int i0 = (int)out[IDX_OFF + n + 0];
  const int i1 = (int)out[IDX_OFF + n + 1];
  const int i2 = (int)out[IDX_OFF + n + 2];
  const int i3 = (int)out[IDX_OFF + n + 3];
  const float* e0 = E + (size_t)i0 * D_DIM;
  const float* e1 = E + (size_t)i1 * D_DIM;
  const float* e2 = E + (size_t)i2 * D_DIM;
  const float* e3 = E + (size_t)i3 * D_DIM;
  const int d0 = blockIdx.y * 32;
#pragma unroll 4
  for (int d = d0; d < d0 + 32; ++d) {
    float4 wv = make_float4(e0[d], e1[d], e2[d], e3[d]);
    *(float4*)&out[(size_t)d * N_TOK + n] = wv;
  }
}

extern "C" void kernel_launch(void* const* d_in, const int* in_sizes, int n_in,
                              void* d_out, int out_size, void* d_ws, size_t ws_size,
                              hipStream_t stream) {
  const float* X = (const float*)d_in[0];   // (1, 256, 65536)
  const float* E = (const float*)d_in[1];   // (1, 1024, 256)
  float* out = (float*)d_out;

  hipLaunchKernelGGL(kA_prep, dim3(272), dim3(256), 0, stream, X, E, out);
  hipLaunchKernelGGL(k2_dist, dim3(C_NUM / TC, N_TOK / TM), dim3(256), 0, stream,
                     X, out);
  hipLaunchKernelGGL(k3_argmax, dim3(N_TOK / 16), dim3(256), 0, stream, X, E, out);
  hipLaunchKernelGGL(k3b_loss, dim3(1), dim3(256), 0, stream, out);
  hipLaunchKernelGGL(k4_gather, dim3(N_TOK / 4 / 256, 8), dim3(256), 0, stream,
                     E, out);
}